// Round 16
// baseline (514.325 us; speedup 1.0000x reference)
//
#include <hip/hip_runtime.h>
#include <hip/hip_bf16.h>
#include <stdint.h>

#define IGNORE_INDEX (-100)

typedef float f32x4 __attribute__((ext_vector_type(4)));
typedef int i32x4 __attribute__((ext_vector_type(4)));

constexpr int NTOK = 4096;
constexpr int HID  = 2048;
constexpr int VOC  = 32000;
constexpr int BM = 128, BN = 128, BKB = 64;   // K-bytes per tile (64 i8)
constexpr int NT_N = VOC / BN;   // 250 n-tiles
constexpr int NT_M = NTOK / BM;  // 32 m-tiles
constexpr int KSTEPS = HID / 64; // 32 k-steps

// Integer quantization (int32 accumulate is exact; descale in epilogue):
//   X stored as i8(rne(X * 16)),  W stored as i8(rne(W * 1024))
#define XSCALE 16.0f
#define WSCALE 1024.0f
#define INV_SCALE (1.0f / 16384.0f)

// ---- ws layout (bytes) ----
// Wi8   @ 0         : 32000*2048 = 65,536,000   (row-major)
// Xfrag @ 65536000  :  4096*2048 =  8,388,608   (MFMA-fragment order)
// pmax  @ 73924608  : 250*4096*4 =  4,096,000   ([ntile][row])
// psum  @ 78020608  : 250*4096*4 =  4,096,000
// xt    @ 82116608  :     4096*4
// loss  @ 82132992  :     4096*4

__device__ __forceinline__ unsigned q8(float v, float s) {
  int q = __float2int_rn(v * s);
  q = max(-127, min(127, q));
  return (unsigned)(q & 0xff);
}

__device__ __forceinline__ unsigned pack4(float4 a, float s) {
  return q8(a.x, s) | (q8(a.y, s) << 8) | (q8(a.z, s) << 16) | (q8(a.w, s) << 24);
}

// row-major i8 quantize (for W) — R10-verified
__global__ void cvti8_kernel(const float* __restrict__ src, uint2* __restrict__ dst,
                             size_t n8, float scale) {
  size_t i = (size_t)blockIdx.x * blockDim.x + threadIdx.x;
  size_t stride = (size_t)gridDim.x * blockDim.x;
  const float4* s4 = reinterpret_cast<const float4*>(src);
  for (; i < n8; i += stride) {
    float4 a = s4[2 * i];
    float4 b = s4[2 * i + 1];
    dst[i] = make_uint2(pack4(a, scale), pack4(b, scale));
  }
}

// quantize + rearrange into MFMA-fragment order (for X) — R13/R15-verified.
// frag addr for (row,k): ((row>>4)*KSTEPS + (k>>6))*1024 + ((k>>4)&3)*256
//                        + (row&15)*16 + (k&15)
__global__ void cvtfrag_kernel(const float* __restrict__ src, uint4* __restrict__ dst,
                               int nrows, float scale) {
  int u = blockIdx.x * blockDim.x + threadIdx.x;
  int total = nrows * 128;
  int stride = gridDim.x * blockDim.x;
  const float4* s4 = reinterpret_cast<const float4*>(src);
  for (; u < total; u += stride) {
    int row = u >> 7;
    int kc = u & 127;                       // 16-value k-chunk index
    const float4* p = s4 + ((size_t)row * 512 + kc * 4);
    float4 a = p[0], b = p[1], c = p[2], d = p[3];
    uint4 o;
    o.x = pack4(a, scale); o.y = pack4(b, scale);
    o.z = pack4(c, scale); o.w = pack4(d, scale);
    size_t fi = ((size_t)(row >> 4) * KSTEPS + (kc >> 2)) * 64 + (kc & 3) * 16 + (row & 15);
    dst[fi] = o;
  }
}

// x_t[row] = dot(X[row], W[target[row]]) + bias[target[row]]   (fp32, exact)
__global__ void xt_kernel(const float* __restrict__ X, const float* __restrict__ W,
                          const float* __restrict__ bias, const int* __restrict__ tgt,
                          float* __restrict__ xt) {
  int row = blockIdx.x * 4 + (threadIdx.x >> 6);
  int lane = threadIdx.x & 63;
  if (row >= NTOK) return;
  int t = tgt[row];
  if (t < 0 || t >= VOC) { if (lane == 0) xt[row] = 0.0f; return; }
  const float4* xr = reinterpret_cast<const float4*>(X + (size_t)row * HID);
  const float4* wr = reinterpret_cast<const float4*>(W + (size_t)t * HID);
  float s = 0.0f;
  for (int i = lane; i < HID / 4; i += 64) {
    float4 a = xr[i], b = wr[i];
    s += a.x * b.x + a.y * b.y + a.z * b.z + a.w * b.w;
  }
#pragma unroll
  for (int d = 1; d < 64; d <<= 1) s += __shfl_xor(s, d);
  if (lane == 0) xt[row] = s + bias[t];
}

// Fused i8 GEMM (logits tile) + per-row (max, sumexp) partials.
// R15 hybrid (B via LDS, A via fragment-ordered global) + counted-vmcnt
// pipeline that the compiler CANNOT undo:
//  - A-loads are asm volatile global_load_dwordx4 into named E/O buffers
//    (cannot be sunk past MFMA — the R13/R14 failure mode);
//  - B is double-buffered in LDS (2 slabs), so the per-iter wait is
//    vmcnt(6)/vmcnt(4) instead of __syncthreads' vmcnt(0) drain.
// vmcnt ledger (in-order retirement; per body t, issue glds(t+1)^2, A(t+1)^4):
//   pre-MFMA  vmcnt(6) -> A(t) drained (6 = exactly the newer ops);
//   post-MFMA vmcnt(4) -> glds(t+1) drained before barrier, so next iter's
//   ds_read of that slab is safe; A(t+1) stays in flight across the barrier.
// Slab parity compile-time (even/odd bodies); sched_barrier(0) after each
// asm wait (hipcc hoists reg-only MFMA past asm waitcnt otherwise).
// Race audit: slab p's last ds_reads complete before each wave's barrier
// arrival (lgkmcnt before MFMA); glds into p issued only after that barrier.
__global__ __launch_bounds__(256, 4) void gemm_lse_kernel(
    const uint8_t* __restrict__ Xf, const uint8_t* __restrict__ Wi8,
    const float* __restrict__ bias,
    float* __restrict__ pmax, float* __restrict__ psum) {
  __shared__ __align__(16) uint8_t Bs[2][BN * BKB];  // 2 x 8 KB
  __shared__ float redM[2][BM];
  __shared__ float redS[2][BM];

  // XCD-chunked swizzle, mtile-fastest (8000 % 8 == 0, bijective)
  const int nwg = NT_M * NT_N;           // 8000
  const int xcd = blockIdx.x & 7;
  const int pos = blockIdx.x >> 3;
  const int wgid = xcd * (nwg >> 3) + pos;
  const int mtile = wgid & (NT_M - 1);   // 32 consecutive blocks share W panel
  const int ntile = wgid >> 5;
  const int mbase = mtile * BM;
  const int nbase = ntile * BN;

  const int tid = threadIdx.x;
  const int w = tid >> 6;                // 0..3
  const int lane = tid & 63;
  const int wr = w >> 1, wc = w & 1;     // wave -> 64x64 output sub-tile
  const int l15 = lane & 15;
  const int kgrp = lane >> 4;            // 0..3

  // ---- B staging (R10-identical maps): linear LDS dest, inv-swizzled src ----
  const int srow = tid >> 2;                          // 0..63
  const int csrc = (tid & 3) ^ ((tid >> 3) & 3);
  const uint8_t* bSt0 = Wi8 + (size_t)(nbase + srow) * HID + csrc * 16;
  const uint8_t* bSt1 = bSt0 + (size_t)64 * HID;      // rows +64

  // B ds_read (R10-identical): slot = kgrp ^ ((l15>>1)&3)
  const int swz16 = (kgrp ^ ((l15 >> 1) & 3)) * 16;
  const int brow0 = wc * 64 + l15;

  // ---- A fragment pointers (R13/R15-verified addressing) ----
  const int lofs = kgrp * 256 + l15 * 16;
  const uint8_t* aQ0 = Xf + ((size_t)((mbase >> 4) + wr * 4 + 0) * KSTEPS) * 1024 + lofs;
  const uint8_t* aQ1 = Xf + ((size_t)((mbase >> 4) + wr * 4 + 1) * KSTEPS) * 1024 + lofs;
  const uint8_t* aQ2 = Xf + ((size_t)((mbase >> 4) + wr * 4 + 2) * KSTEPS) * 1024 + lofs;
  const uint8_t* aQ3 = Xf + ((size_t)((mbase >> 4) + wr * 4 + 3) * KSTEPS) * 1024 + lofs;

  i32x4 acc[4][4];
#pragma unroll
  for (int mi = 0; mi < 4; ++mi)
#pragma unroll
    for (int ni = 0; ni < 4; ++ni)
#pragma unroll
      for (int j = 0; j < 4; ++j) acc[mi][ni][j] = 0;

  float bv[4];
#pragma unroll
  for (int ni = 0; ni < 4; ++ni) bv[ni] = bias[nbase + wc * 64 + ni * 16 + l15];

#define GLDS(SRC, DST)                                                              \
  __builtin_amdgcn_global_load_lds((const __attribute__((address_space(1))) void*)(SRC), \
                                   (__attribute__((address_space(3))) void*)(DST), 16, 0, 0)
#define STAGE_B(TK, SLAB)                                                           \
  { GLDS(bSt0 + (TK) * 64, &Bs[(SLAB)][tid * 16]);                                  \
    GLDS(bSt1 + (TK) * 64, &Bs[(SLAB)][4096 + tid * 16]); }
#define ALOAD4(AF, TK)                                                              \
  { asm volatile("global_load_dwordx4 %0, %1, off" : "=v"(AF[0]) : "v"(aQ0 + (size_t)(TK) * 1024)); \
    asm volatile("global_load_dwordx4 %0, %1, off" : "=v"(AF[1]) : "v"(aQ1 + (size_t)(TK) * 1024)); \
    asm volatile("global_load_dwordx4 %0, %1, off" : "=v"(AF[2]) : "v"(aQ2 + (size_t)(TK) * 1024)); \
    asm volatile("global_load_dwordx4 %0, %1, off" : "=v"(AF[3]) : "v"(aQ3 + (size_t)(TK) * 1024)); }
#define BREAD(BG, SLAB)                                                             \
  _Pragma("unroll")                                                                 \
  for (int ni = 0; ni < 4; ++ni)                                                    \
    BG[ni] = *reinterpret_cast<const i32x4*>(&Bs[(SLAB)][(brow0 + ni * 16) * BKB + swz16]);
#define MFMA16(AF, BG)                                                              \
  _Pragma("unroll")                                                                 \
  for (int mi = 0; mi < 4; ++mi)                                                    \
    _Pragma("unroll")                                                               \
    for (int ni = 0; ni < 4; ++ni)                                                  \
      acc[mi][ni] = __builtin_amdgcn_mfma_i32_16x16x64_i8(AF[mi], BG[ni],           \
                                                          acc[mi][ni], 0, 0, 0);
// BODY: stage B(t+1)->SLABN, read B(t) from SLABC, load A(t+1)->AFN,
//       vmcnt(6) [A(t) done], MFMA(AFC), vmcnt(4) [glds(t+1) done], barrier.
#define BODY(T, SLABC, SLABN, AFC, AFN)                                             \
  { STAGE_B((T) + 1, SLABN)                                                         \
    i32x4 bg[4];                                                                    \
    BREAD(bg, SLABC)                                                                \
    ALOAD4(AFN, (T) + 1)                                                            \
    asm volatile("s_waitcnt vmcnt(6)" ::: "memory");                                \
    __builtin_amdgcn_sched_barrier(0);                                              \
    MFMA16(AFC, bg)                                                                 \
    __builtin_amdgcn_sched_barrier(0);                                              \
    asm volatile("s_waitcnt vmcnt(4)" ::: "memory");                                \
    __builtin_amdgcn_s_barrier();                                                   \
    asm volatile("" ::: "memory"); }

  i32x4 afE[4], afO[4];
  // prologue: B(0) -> slab0, A(0) -> afE; full drain; barrier
  STAGE_B(0, 0)
  ALOAD4(afE, 0)
  asm volatile("s_waitcnt vmcnt(0)" ::: "memory");
  __builtin_amdgcn_s_barrier();
  asm volatile("" ::: "memory");

  // main loop: pairs (even reads slab0, odd reads slab1); KSTEPS = 32
  for (int tt = 0; tt < KSTEPS - 2; tt += 2) {
    BODY(tt,     0, 1, afE, afO)
    BODY(tt + 1, 1, 0, afO, afE)
  }
  // t = 30 (even): stage B(31)->slab1, load A(31)->afO
  BODY(KSTEPS - 2, 0, 1, afE, afO)
  // t = 31 (odd, last): no more staging; drain A(31) then compute
  {
    i32x4 bg[4];
    BREAD(bg, 1)
    asm volatile("s_waitcnt vmcnt(0)" ::: "memory");
    __builtin_amdgcn_sched_barrier(0);
    MFMA16(afO, bg)
  }

#undef BODY
#undef MFMA16
#undef BREAD
#undef ALOAD4
#undef STAGE_B
#undef GLDS

  // ---- epilogue: per-row (max, sumexp) over this block's 128 cols ----
  // C frag (16x16, dtype-independent): col = l15, row = kgrp*4 + j.
  // Descale 1/16384 folded into the bias FMA.
#pragma unroll
  for (int mi = 0; mi < 4; ++mi) {
#pragma unroll
    for (int j = 0; j < 4; ++j) {
      float v0 = fmaf((float)acc[mi][0][j], INV_SCALE, bv[0]);
      float v1 = fmaf((float)acc[mi][1][j], INV_SCALE, bv[1]);
      float v2 = fmaf((float)acc[mi][2][j], INV_SCALE, bv[2]);
      float v3 = fmaf((float)acc[mi][3][j], INV_SCALE, bv[3]);
      float mx = fmaxf(fmaxf(v0, v1), fmaxf(v2, v3));
#pragma unroll
      for (int d = 1; d < 16; d <<= 1) mx = fmaxf(mx, __shfl_xor(mx, d));
      float s = __expf(v0 - mx) + __expf(v1 - mx) + __expf(v2 - mx) + __expf(v3 - mx);
#pragma unroll
      for (int d = 1; d < 16; d <<= 1) s += __shfl_xor(s, d);
      if (l15 == 0) {
        int lr = wr * 64 + mi * 16 + kgrp * 4 + j;
        redM[wc][lr] = mx;
        redS[wc][lr] = s;
      }
    }
  }
  __syncthreads();
  if (tid < BM) {
    float m0 = redM[0][tid], m1 = redM[1][tid];
    float M = fmaxf(m0, m1);
    float S = __expf(m0 - M) * redS[0][tid] + __expf(m1 - M) * redS[1][tid];
    size_t row = (size_t)mbase + tid;
    pmax[(size_t)ntile * NTOK + row] = M;   // coalesced over tid
    psum[(size_t)ntile * NTOK + row] = S;
  }
}

// merge 250 partials per row -> lse -> per-row loss
__global__ void lse_kernel(const float* __restrict__ pmax, const float* __restrict__ psum,
                           const float* __restrict__ xt, const int* __restrict__ tgt,
                           float* __restrict__ loss) {
  int row = blockIdx.x * 4 + (threadIdx.x >> 6);
  int lane = threadIdx.x & 63;
  if (row >= NTOK) return;
  float M = -3.4e38f;
  for (int i = lane; i < NT_N; i += 64) M = fmaxf(M, pmax[(size_t)i * NTOK + row]);
#pragma unroll
  for (int d = 1; d < 64; d <<= 1) M = fmaxf(M, __shfl_xor(M, d));
  float S = 0.0f;
  for (int i = lane; i < NT_N; i += 64)
    S += __expf(pmax[(size_t)i * NTOK + row] - M) * psum[(size_t)i * NTOK + row];
#pragma unroll
  for (int d = 1; d < 64; d <<= 1) S += __shfl_xor(S, d);
  if (lane == 0) {
    int tg = tgt[row];
    bool valid = (tg != IGNORE_INDEX);
    float lse = M + __logf(S);
    loss[row] = valid ? (lse - xt[row]) : 0.0f;
  }
}

__global__ void final_kernel(const float* __restrict__ loss, const int* __restrict__ tgt,
                             float* __restrict__ out) {
  __shared__ float shs[256];
  __shared__ float shc[256];
  int tid = threadIdx.x;
  float s = 0.0f, c = 0.0f;
  for (int i = tid; i < NTOK; i += 256) {
    s += loss[i];
    c += (tgt[i] != IGNORE_INDEX) ? 1.0f : 0.0f;
  }
  shs[tid] = s; shc[tid] = c;
  __syncthreads();
  for (int off = 128; off > 0; off >>= 1) {
    if (tid < off) { shs[tid] += shs[tid + off]; shc[tid] += shc[tid + off]; }
    __syncthreads();
  }
  if (tid == 0) out[0] = shs[0] / fmaxf(shc[0], 1.0f);
}

extern "C" void kernel_launch(void* const* d_in, const int* in_sizes, int n_in,
                              void* d_out, int out_size, void* d_ws, size_t ws_size,
                              hipStream_t stream) {
  const float* W    = (const float*)d_in[0];  // [32000][2048]
  const float* X    = (const float*)d_in[1];  // [4096][2048]
  const int*   tgt  = (const int*)d_in[2];    // [4096]
  const float* bias = (const float*)d_in[3];  // [32000]
  float* out = (float*)d_out;

  char* ws = (char*)d_ws;
  uint8_t* Wi8 = (uint8_t*)(ws);
  uint8_t* Xf  = (uint8_t*)(ws + 65536000);
  float* pmax  = (float*)  (ws + 73924608);
  float* psum  = (float*)  (ws + 78020608);
  float* xt    = (float*)  (ws + 82116608);
  float* loss  = (float*)  (ws + 82132992);

  cvti8_kernel<<<2048, 256, 0, stream>>>(W, (uint2*)Wi8, (size_t)VOC * HID / 8, WSCALE);
  cvtfrag_kernel<<<1024, 256, 0, stream>>>(X, (uint4*)Xf, NTOK, XSCALE);
  xt_kernel<<<NTOK / 4, 256, 0, stream>>>(X, W, bias, tgt, xt);
  gemm_lse_kernel<<<NT_M * NT_N, 256, 0, stream>>>(Xf, Wi8, bias, pmax, psum);
  lse_kernel<<<NTOK / 4, 256, 0, stream>>>(pmax, psum, xt, tgt, loss);
  final_kernel<<<1, 256, 0, stream>>>(loss, tgt, out);
}

// Round 17
// 444.631 us; speedup vs baseline: 1.1567x; 1.1567x over previous
//
#include <hip/hip_runtime.h>
#include <hip/hip_bf16.h>
#include <stdint.h>

#define IGNORE_INDEX (-100)

typedef float f32x4 __attribute__((ext_vector_type(4)));
typedef int i32x4 __attribute__((ext_vector_type(4)));

constexpr int NTOK = 4096;
constexpr int HID  = 2048;
constexpr int VOC  = 32000;
constexpr int BM = 128, BN = 128, BKB = 64;   // K-bytes per tile (64 i8)
constexpr int NT_N = VOC / BN;   // 250 n-tiles
constexpr int NT_M = NTOK / BM;  // 32 m-tiles
constexpr int KSTEPS = HID / 64; // 32 k-steps

// Integer quantization (int32 accumulate is exact; descale in epilogue):
//   X stored as i8(rne(X * 16)),  W stored as i8(rne(W * 1024))
#define XSCALE 16.0f
#define WSCALE 1024.0f
#define INV_SCALE (1.0f / 16384.0f)

// ---- ws layout (bytes) ----
// Wi8   @ 0         : 32000*2048 = 65,536,000   (row-major)
// Xfrag @ 65536000  :  4096*2048 =  8,388,608   (MFMA-fragment order)
// pmax  @ 73924608  : 250*4096*4 =  4,096,000   ([ntile][row])
// psum  @ 78020608  : 250*4096*4 =  4,096,000
// xt    @ 82116608  :     4096*4
// loss  @ 82132992  :     4096*4

__device__ __forceinline__ unsigned q8(float v, float s) {
  int q = __float2int_rn(v * s);
  q = max(-127, min(127, q));
  return (unsigned)(q & 0xff);
}

__device__ __forceinline__ unsigned pack4(float4 a, float s) {
  return q8(a.x, s) | (q8(a.y, s) << 8) | (q8(a.z, s) << 16) | (q8(a.w, s) << 24);
}

// row-major i8 quantize (for W) — R10-verified
__global__ void cvti8_kernel(const float* __restrict__ src, uint2* __restrict__ dst,
                             size_t n8, float scale) {
  size_t i = (size_t)blockIdx.x * blockDim.x + threadIdx.x;
  size_t stride = (size_t)gridDim.x * blockDim.x;
  const float4* s4 = reinterpret_cast<const float4*>(src);
  for (; i < n8; i += stride) {
    float4 a = s4[2 * i];
    float4 b = s4[2 * i + 1];
    dst[i] = make_uint2(pack4(a, scale), pack4(b, scale));
  }
}

// quantize + rearrange into MFMA-fragment order (for X) — R13/R15-verified.
// frag addr for (row,k): ((row>>4)*KSTEPS + (k>>6))*1024 + ((k>>4)&3)*256
//                        + (row&15)*16 + (k&15)
__global__ void cvtfrag_kernel(const float* __restrict__ src, uint4* __restrict__ dst,
                               int nrows, float scale) {
  int u = blockIdx.x * blockDim.x + threadIdx.x;
  int total = nrows * 128;
  int stride = gridDim.x * blockDim.x;
  const float4* s4 = reinterpret_cast<const float4*>(src);
  for (; u < total; u += stride) {
    int row = u >> 7;
    int kc = u & 127;                       // 16-value k-chunk index
    const float4* p = s4 + ((size_t)row * 512 + kc * 4);
    float4 a = p[0], b = p[1], c = p[2], d = p[3];
    uint4 o;
    o.x = pack4(a, scale); o.y = pack4(b, scale);
    o.z = pack4(c, scale); o.w = pack4(d, scale);
    size_t fi = ((size_t)(row >> 4) * KSTEPS + (kc >> 2)) * 64 + (kc & 3) * 16 + (row & 15);
    dst[fi] = o;
  }
}

// x_t[row] = dot(X[row], W[target[row]]) + bias[target[row]]   (fp32, exact)
__global__ void xt_kernel(const float* __restrict__ X, const float* __restrict__ W,
                          const float* __restrict__ bias, const int* __restrict__ tgt,
                          float* __restrict__ xt) {
  int row = blockIdx.x * 4 + (threadIdx.x >> 6);
  int lane = threadIdx.x & 63;
  if (row >= NTOK) return;
  int t = tgt[row];
  if (t < 0 || t >= VOC) { if (lane == 0) xt[row] = 0.0f; return; }
  const float4* xr = reinterpret_cast<const float4*>(X + (size_t)row * HID);
  const float4* wr = reinterpret_cast<const float4*>(W + (size_t)t * HID);
  float s = 0.0f;
  for (int i = lane; i < HID / 4; i += 64) {
    float4 a = xr[i], b = wr[i];
    s += a.x * b.x + a.y * b.y + a.z * b.z + a.w * b.w;
  }
#pragma unroll
  for (int d = 1; d < 64; d <<= 1) s += __shfl_xor(s, d);
  if (lane == 0) xt[row] = s + bias[t];
}

// Fused i8 GEMM (logits tile) + per-row (max, sumexp) partials.
// R16 pipeline (B dbuf-LDS + asm A-loads + counted vmcnt) with the ONE fix
// its failure demanded: __launch_bounds__(256,3) -> 170-reg budget, no spill
// (R16 @ (256,4) was strangled to 64 regs -> 144MB scratch, confounding the
// pipeline test). This is the clean test of 3-block/CU + real pipeline vs
// R15's 4-block/CU + per-iter vmcnt(0) drain.
// vmcnt ledger unchanged from R16 (audited): per body t issue glds(t+1)^2
// then A(t+1)^4; pre-MFMA vmcnt(6) drains A(t); post-MFMA vmcnt(4) drains
// glds(t+1) before the barrier; A(t+1) rides through the barrier.
__global__ __launch_bounds__(256, 3) void gemm_lse_kernel(
    const uint8_t* __restrict__ Xf, const uint8_t* __restrict__ Wi8,
    const float* __restrict__ bias,
    float* __restrict__ pmax, float* __restrict__ psum) {
  __shared__ __align__(16) uint8_t Bs[2][BN * BKB];  // 2 x 8 KB
  __shared__ float redM[2][BM];
  __shared__ float redS[2][BM];

  // XCD-chunked swizzle, mtile-fastest (8000 % 8 == 0, bijective)
  const int nwg = NT_M * NT_N;           // 8000
  const int xcd = blockIdx.x & 7;
  const int pos = blockIdx.x >> 3;
  const int wgid = xcd * (nwg >> 3) + pos;
  const int mtile = wgid & (NT_M - 1);   // 32 consecutive blocks share W panel
  const int ntile = wgid >> 5;
  const int mbase = mtile * BM;
  const int nbase = ntile * BN;

  const int tid = threadIdx.x;
  const int w = tid >> 6;                // 0..3
  const int lane = tid & 63;
  const int wr = w >> 1, wc = w & 1;     // wave -> 64x64 output sub-tile
  const int l15 = lane & 15;
  const int kgrp = lane >> 4;            // 0..3

  // ---- B staging (R10-identical maps): linear LDS dest, inv-swizzled src ----
  const int srow = tid >> 2;                          // 0..63
  const int csrc = (tid & 3) ^ ((tid >> 3) & 3);
  const uint8_t* bSt0 = Wi8 + (size_t)(nbase + srow) * HID + csrc * 16;
  const uint8_t* bSt1 = bSt0 + (size_t)64 * HID;      // rows +64

  // B ds_read (R10-identical): slot = kgrp ^ ((l15>>1)&3)
  const int swz16 = (kgrp ^ ((l15 >> 1) & 3)) * 16;
  const int brow0 = wc * 64 + l15;

  // ---- A fragment pointers (R13/R15-verified addressing) ----
  const int lofs = kgrp * 256 + l15 * 16;
  const uint8_t* aQ0 = Xf + ((size_t)((mbase >> 4) + wr * 4 + 0) * KSTEPS) * 1024 + lofs;
  const uint8_t* aQ1 = Xf + ((size_t)((mbase >> 4) + wr * 4 + 1) * KSTEPS) * 1024 + lofs;
  const uint8_t* aQ2 = Xf + ((size_t)((mbase >> 4) + wr * 4 + 2) * KSTEPS) * 1024 + lofs;
  const uint8_t* aQ3 = Xf + ((size_t)((mbase >> 4) + wr * 4 + 3) * KSTEPS) * 1024 + lofs;

  i32x4 acc[4][4];
#pragma unroll
  for (int mi = 0; mi < 4; ++mi)
#pragma unroll
    for (int ni = 0; ni < 4; ++ni)
#pragma unroll
      for (int j = 0; j < 4; ++j) acc[mi][ni][j] = 0;

  float bv[4];
#pragma unroll
  for (int ni = 0; ni < 4; ++ni) bv[ni] = bias[nbase + wc * 64 + ni * 16 + l15];

#define GLDS(SRC, DST)                                                              \
  __builtin_amdgcn_global_load_lds((const __attribute__((address_space(1))) void*)(SRC), \
                                   (__attribute__((address_space(3))) void*)(DST), 16, 0, 0)
#define STAGE_B(TK, SLAB)                                                           \
  { GLDS(bSt0 + (TK) * 64, &Bs[(SLAB)][tid * 16]);                                  \
    GLDS(bSt1 + (TK) * 64, &Bs[(SLAB)][4096 + tid * 16]); }
#define ALOAD4(AF, TK)                                                              \
  { asm volatile("global_load_dwordx4 %0, %1, off" : "=v"(AF[0]) : "v"(aQ0 + (size_t)(TK) * 1024)); \
    asm volatile("global_load_dwordx4 %0, %1, off" : "=v"(AF[1]) : "v"(aQ1 + (size_t)(TK) * 1024)); \
    asm volatile("global_load_dwordx4 %0, %1, off" : "=v"(AF[2]) : "v"(aQ2 + (size_t)(TK) * 1024)); \
    asm volatile("global_load_dwordx4 %0, %1, off" : "=v"(AF[3]) : "v"(aQ3 + (size_t)(TK) * 1024)); }
#define BREAD(BG, SLAB)                                                             \
  _Pragma("unroll")                                                                 \
  for (int ni = 0; ni < 4; ++ni)                                                    \
    BG[ni] = *reinterpret_cast<const i32x4*>(&Bs[(SLAB)][(brow0 + ni * 16) * BKB + swz16]);
#define MFMA16(AF, BG)                                                              \
  _Pragma("unroll")                                                                 \
  for (int mi = 0; mi < 4; ++mi)                                                    \
    _Pragma("unroll")                                                               \
    for (int ni = 0; ni < 4; ++ni)                                                  \
      acc[mi][ni] = __builtin_amdgcn_mfma_i32_16x16x64_i8(AF[mi], BG[ni],           \
                                                          acc[mi][ni], 0, 0, 0);
// BODY: stage B(t+1)->SLABN, read B(t) from SLABC, load A(t+1)->AFN,
//       vmcnt(6) [A(t) done], MFMA(AFC), vmcnt(4) [glds(t+1) done], barrier.
#define BODY(T, SLABC, SLABN, AFC, AFN)                                             \
  { STAGE_B((T) + 1, SLABN)                                                         \
    i32x4 bg[4];                                                                    \
    BREAD(bg, SLABC)                                                                \
    ALOAD4(AFN, (T) + 1)                                                            \
    asm volatile("s_waitcnt vmcnt(6)" ::: "memory");                                \
    __builtin_amdgcn_sched_barrier(0);                                              \
    MFMA16(AFC, bg)                                                                 \
    __builtin_amdgcn_sched_barrier(0);                                              \
    asm volatile("s_waitcnt vmcnt(4)" ::: "memory");                                \
    __builtin_amdgcn_s_barrier();                                                   \
    asm volatile("" ::: "memory"); }

  i32x4 afE[4], afO[4];
  // prologue: B(0) -> slab0, A(0) -> afE; full drain; barrier
  STAGE_B(0, 0)
  ALOAD4(afE, 0)
  asm volatile("s_waitcnt vmcnt(0)" ::: "memory");
  __builtin_amdgcn_s_barrier();
  asm volatile("" ::: "memory");

  // main loop: pairs (even reads slab0, odd reads slab1); KSTEPS = 32
  for (int tt = 0; tt < KSTEPS - 2; tt += 2) {
    BODY(tt,     0, 1, afE, afO)
    BODY(tt + 1, 1, 0, afO, afE)
  }
  // t = 30 (even): stage B(31)->slab1, load A(31)->afO
  BODY(KSTEPS - 2, 0, 1, afE, afO)
  // t = 31 (odd, last): no more staging; drain A(31) then compute
  {
    i32x4 bg[4];
    BREAD(bg, 1)
    asm volatile("s_waitcnt vmcnt(0)" ::: "memory");
    __builtin_amdgcn_sched_barrier(0);
    MFMA16(afO, bg)
  }

#undef BODY
#undef MFMA16
#undef BREAD
#undef ALOAD4
#undef STAGE_B
#undef GLDS

  // ---- epilogue: per-row (max, sumexp) over this block's 128 cols ----
  // C frag (16x16, dtype-independent): col = l15, row = kgrp*4 + j.
  // Descale 1/16384 folded into the bias FMA.
#pragma unroll
  for (int mi = 0; mi < 4; ++mi) {
#pragma unroll
    for (int j = 0; j < 4; ++j) {
      float v0 = fmaf((float)acc[mi][0][j], INV_SCALE, bv[0]);
      float v1 = fmaf((float)acc[mi][1][j], INV_SCALE, bv[1]);
      float v2 = fmaf((float)acc[mi][2][j], INV_SCALE, bv[2]);
      float v3 = fmaf((float)acc[mi][3][j], INV_SCALE, bv[3]);
      float mx = fmaxf(fmaxf(v0, v1), fmaxf(v2, v3));
#pragma unroll
      for (int d = 1; d < 16; d <<= 1) mx = fmaxf(mx, __shfl_xor(mx, d));
      float s = __expf(v0 - mx) + __expf(v1 - mx) + __expf(v2 - mx) + __expf(v3 - mx);
#pragma unroll
      for (int d = 1; d < 16; d <<= 1) s += __shfl_xor(s, d);
      if (l15 == 0) {
        int lr = wr * 64 + mi * 16 + kgrp * 4 + j;
        redM[wc][lr] = mx;
        redS[wc][lr] = s;
      }
    }
  }
  __syncthreads();
  if (tid < BM) {
    float m0 = redM[0][tid], m1 = redM[1][tid];
    float M = fmaxf(m0, m1);
    float S = __expf(m0 - M) * redS[0][tid] + __expf(m1 - M) * redS[1][tid];
    size_t row = (size_t)mbase + tid;
    pmax[(size_t)ntile * NTOK + row] = M;   // coalesced over tid
    psum[(size_t)ntile * NTOK + row] = S;
  }
}

// merge 250 partials per row -> lse -> per-row loss
__global__ void lse_kernel(const float* __restrict__ pmax, const float* __restrict__ psum,
                           const float* __restrict__ xt, const int* __restrict__ tgt,
                           float* __restrict__ loss) {
  int row = blockIdx.x * 4 + (threadIdx.x >> 6);
  int lane = threadIdx.x & 63;
  if (row >= NTOK) return;
  float M = -3.4e38f;
  for (int i = lane; i < NT_N; i += 64) M = fmaxf(M, pmax[(size_t)i * NTOK + row]);
#pragma unroll
  for (int d = 1; d < 64; d <<= 1) M = fmaxf(M, __shfl_xor(M, d));
  float S = 0.0f;
  for (int i = lane; i < NT_N; i += 64)
    S += __expf(pmax[(size_t)i * NTOK + row] - M) * psum[(size_t)i * NTOK + row];
#pragma unroll
  for (int d = 1; d < 64; d <<= 1) S += __shfl_xor(S, d);
  if (lane == 0) {
    int tg = tgt[row];
    bool valid = (tg != IGNORE_INDEX);
    float lse = M + __logf(S);
    loss[row] = valid ? (lse - xt[row]) : 0.0f;
  }
}

__global__ void final_kernel(const float* __restrict__ loss, const int* __restrict__ tgt,
                             float* __restrict__ out) {
  __shared__ float shs[256];
  __shared__ float shc[256];
  int tid = threadIdx.x;
  float s = 0.0f, c = 0.0f;
  for (int i = tid; i < NTOK; i += 256) {
    s += loss[i];
    c += (tgt[i] != IGNORE_INDEX) ? 1.0f : 0.0f;
  }
  shs[tid] = s; shc[tid] = c;
  __syncthreads();
  for (int off = 128; off > 0; off >>= 1) {
    if (tid < off) { shs[tid] += shs[tid + off]; shc[tid] += shc[tid + off]; }
    __syncthreads();
  }
  if (tid == 0) out[0] = shs[0] / fmaxf(shc[0], 1.0f);
}

extern "C" void kernel_launch(void* const* d_in, const int* in_sizes, int n_in,
                              void* d_out, int out_size, void* d_ws, size_t ws_size,
                              hipStream_t stream) {
  const float* W    = (const float*)d_in[0];  // [32000][2048]
  const float* X    = (const float*)d_in[1];  // [4096][2048]
  const int*   tgt  = (const int*)d_in[2];    // [4096]
  const float* bias = (const float*)d_in[3];  // [32000]
  float* out = (float*)d_out;

  char* ws = (char*)d_ws;
  uint8_t* Wi8 = (uint8_t*)(ws);
  uint8_t* Xf  = (uint8_t*)(ws + 65536000);
  float* pmax  = (float*)  (ws + 73924608);
  float* psum  = (float*)  (ws + 78020608);
  float* xt    = (float*)  (ws + 82116608);
  float* loss  = (float*)  (ws + 82132992);

  cvti8_kernel<<<2048, 256, 0, stream>>>(W, (uint2*)Wi8, (size_t)VOC * HID / 8, WSCALE);
  cvtfrag_kernel<<<1024, 256, 0, stream>>>(X, (uint4*)Xf, NTOK, XSCALE);
  xt_kernel<<<NTOK / 4, 256, 0, stream>>>(X, W, bias, tgt, xt);
  gemm_lse_kernel<<<NT_M * NT_N, 256, 0, stream>>>(Xf, Wi8, bias, pmax, psum);
  lse_kernel<<<NTOK / 4, 256, 0, stream>>>(pmax, psum, xt, tgt, loss);
  final_kernel<<<1, 256, 0, stream>>>(loss, tgt, out);
}

// Round 18
// 425.579 us; speedup vs baseline: 1.2085x; 1.0448x over previous
//
#include <hip/hip_runtime.h>
#include <hip/hip_bf16.h>
#include <stdint.h>

#define IGNORE_INDEX (-100)

typedef float f32x4 __attribute__((ext_vector_type(4)));
typedef int i32x4 __attribute__((ext_vector_type(4)));

constexpr int NTOK = 4096;
constexpr int HID  = 2048;
constexpr int VOC  = 32000;
constexpr int BM = 128, BN = 128, BKB = 64;   // K-bytes per tile (64 i8)
constexpr int NT_N = VOC / BN;   // 250 n-tiles
constexpr int NT_M = NTOK / BM;  // 32 m-tiles
constexpr int KSTEPS = HID / 64; // 32 k-steps

// Integer quantization (int32 accumulate is exact; descale in epilogue):
//   X stored as i8(rne(X * 16)),  W stored as i8(rne(W * 1024))
#define XSCALE 16.0f
#define WSCALE 1024.0f
#define INV_SCALE (1.0f / 16384.0f)

// ---- ws layout (bytes) ----
// Wi8   @ 0         : 32000*2048 = 65,536,000   (row-major)
// Xfrag @ 65536000  :  4096*2048 =  8,388,608   (MFMA-fragment order)
// pmax  @ 73924608  : 250*4096*4 =  4,096,000   ([ntile][row])
// psum  @ 78020608  : 250*4096*4 =  4,096,000
// xt    @ 82116608  :     4096*4
// loss  @ 82132992  :     4096*4

__device__ __forceinline__ unsigned q8(float v, float s) {
  int q = __float2int_rn(v * s);
  q = max(-127, min(127, q));
  return (unsigned)(q & 0xff);
}

__device__ __forceinline__ unsigned pack4(float4 a, float s) {
  return q8(a.x, s) | (q8(a.y, s) << 8) | (q8(a.z, s) << 16) | (q8(a.w, s) << 24);
}

// row-major i8 quantize (for W) — R10-verified
__global__ void cvti8_kernel(const float* __restrict__ src, uint2* __restrict__ dst,
                             size_t n8, float scale) {
  size_t i = (size_t)blockIdx.x * blockDim.x + threadIdx.x;
  size_t stride = (size_t)gridDim.x * blockDim.x;
  const float4* s4 = reinterpret_cast<const float4*>(src);
  for (; i < n8; i += stride) {
    float4 a = s4[2 * i];
    float4 b = s4[2 * i + 1];
    dst[i] = make_uint2(pack4(a, scale), pack4(b, scale));
  }
}

// quantize + rearrange into MFMA-fragment order (for X) — R13/R15-verified.
// frag addr for (row,k): ((row>>4)*KSTEPS + (k>>6))*1024 + ((k>>4)&3)*256
//                        + (row&15)*16 + (k&15)
__global__ void cvtfrag_kernel(const float* __restrict__ src, uint4* __restrict__ dst,
                               int nrows, float scale) {
  int u = blockIdx.x * blockDim.x + threadIdx.x;
  int total = nrows * 128;
  int stride = gridDim.x * blockDim.x;
  const float4* s4 = reinterpret_cast<const float4*>(src);
  for (; u < total; u += stride) {
    int row = u >> 7;
    int kc = u & 127;                       // 16-value k-chunk index
    const float4* p = s4 + ((size_t)row * 512 + kc * 4);
    float4 a = p[0], b = p[1], c = p[2], d = p[3];
    uint4 o;
    o.x = pack4(a, scale); o.y = pack4(b, scale);
    o.z = pack4(c, scale); o.w = pack4(d, scale);
    size_t fi = ((size_t)(row >> 4) * KSTEPS + (kc >> 2)) * 64 + (kc & 3) * 16 + (row & 15);
    dst[fi] = o;
  }
}

// x_t[row] = dot(X[row], W[target[row]]) + bias[target[row]]   (fp32, exact)
__global__ void xt_kernel(const float* __restrict__ X, const float* __restrict__ W,
                          const float* __restrict__ bias, const int* __restrict__ tgt,
                          float* __restrict__ xt) {
  int row = blockIdx.x * 4 + (threadIdx.x >> 6);
  int lane = threadIdx.x & 63;
  if (row >= NTOK) return;
  int t = tgt[row];
  if (t < 0 || t >= VOC) { if (lane == 0) xt[row] = 0.0f; return; }
  const float4* xr = reinterpret_cast<const float4*>(X + (size_t)row * HID);
  const float4* wr = reinterpret_cast<const float4*>(W + (size_t)t * HID);
  float s = 0.0f;
  for (int i = lane; i < HID / 4; i += 64) {
    float4 a = xr[i], b = wr[i];
    s += a.x * b.x + a.y * b.y + a.z * b.z + a.w * b.w;
  }
#pragma unroll
  for (int d = 1; d < 64; d <<= 1) s += __shfl_xor(s, d);
  if (lane == 0) xt[row] = s + bias[t];
}

// Fused i8 GEMM (logits tile) + per-row (max, sumexp) partials.
// MEASURED OPTIMUM of the 17-round search (R15: GEMM 336us, total 427us):
//   B (W rows): R10's LDS path — glds w=16, single-buffered 8KB tile,
//     2 __syncthreads/K-iter, measured-zero-conflict swizzle, l15/kgrp reads.
//   A (X rows): straight from fragment-ordered global — 1KB fully-coalesced
//     wave loads from the 8.4MB L2/L3-hot Xf; A-load latency drains at the
//     same pre-barrier vmcnt(0) the glds already pays.
//   4 blocks/CU TLP is the latency-hiding mechanism (one extra resident
//   block beat a hand-pinned 2-deep counted-vmcnt pipeline at 3 blocks —
//   R17: 378us vs this 336us; 7 schedule variants all lost to this).
// mfma_i32_16x16x64_i8 (2x fp8 rate), int32 accumulate exact.
__global__ __launch_bounds__(256, 4) void gemm_lse_kernel(
    const uint8_t* __restrict__ Xf, const uint8_t* __restrict__ Wi8,
    const float* __restrict__ bias,
    float* __restrict__ pmax, float* __restrict__ psum) {
  __shared__ __align__(16) uint8_t Bs[BN * BKB];   // 8 KB
  __shared__ float redM[2][BM];
  __shared__ float redS[2][BM];

  // XCD-chunked swizzle, mtile-fastest (8000 % 8 == 0, bijective)
  const int nwg = NT_M * NT_N;           // 8000
  const int xcd = blockIdx.x & 7;
  const int pos = blockIdx.x >> 3;
  const int wgid = xcd * (nwg >> 3) + pos;
  const int mtile = wgid & (NT_M - 1);   // 32 consecutive blocks share W panel
  const int ntile = wgid >> 5;
  const int mbase = mtile * BM;
  const int nbase = ntile * BN;

  const int tid = threadIdx.x;
  const int w = tid >> 6;                // 0..3
  const int lane = tid & 63;
  const int wr = w >> 1, wc = w & 1;     // wave -> 64x64 output sub-tile
  const int l15 = lane & 15;
  const int kgrp = lane >> 4;            // 0..3

  // ---- B staging (R10-identical): linear LDS dest, inverse-swizzled src ----
  const int srow = tid >> 2;                          // 0..63
  const int csrc = (tid & 3) ^ ((tid >> 3) & 3);
  const uint8_t* bSt0 = Wi8 + (size_t)(nbase + srow) * HID + csrc * 16;
  const uint8_t* bSt1 = bSt0 + (size_t)64 * HID;      // rows +64

  // B ds_read (R10-identical): slot = kgrp ^ ((l15>>1)&3)
  const int swz16 = (kgrp ^ ((l15 >> 1) & 3)) * 16;
  const int brow0 = wc * 64 + l15;

  // ---- A fragment pointers (R13-verified addressing) ----
  const int lofs = kgrp * 256 + l15 * 16;
  const uint8_t* aP[4];
#pragma unroll
  for (int mi = 0; mi < 4; ++mi)
    aP[mi] = Xf + ((size_t)((mbase >> 4) + wr * 4 + mi) * KSTEPS) * 1024 + lofs;

  i32x4 acc[4][4];
#pragma unroll
  for (int mi = 0; mi < 4; ++mi)
#pragma unroll
    for (int ni = 0; ni < 4; ++ni)
#pragma unroll
      for (int j = 0; j < 4; ++j) acc[mi][ni][j] = 0;

  float bv[4];
#pragma unroll
  for (int ni = 0; ni < 4; ++ni) bv[ni] = bias[nbase + wc * 64 + ni * 16 + l15];

#define GLDS(SRC, DST)                                                              \
  __builtin_amdgcn_global_load_lds((const __attribute__((address_space(1))) void*)(SRC), \
                                   (__attribute__((address_space(3))) void*)(DST), 16, 0, 0)

  for (int t = 0; t < KSTEPS; ++t) {
    __syncthreads();
    GLDS(bSt0 + t * 64, Bs + tid * 16);
    GLDS(bSt1 + t * 64, Bs + 4096 + tid * 16);
    i32x4 af[4];
#pragma unroll
    for (int mi = 0; mi < 4; ++mi)
      af[mi] = *reinterpret_cast<const i32x4*>(aP[mi] + (size_t)t * 1024);
    __syncthreads();   // drains vmcnt(0): B staged AND A fragments landed

    i32x4 bg[4];
#pragma unroll
    for (int ni = 0; ni < 4; ++ni)
      bg[ni] = *reinterpret_cast<const i32x4*>(Bs + (brow0 + ni * 16) * BKB + swz16);
#pragma unroll
    for (int mi = 0; mi < 4; ++mi)
#pragma unroll
      for (int ni = 0; ni < 4; ++ni)
        acc[mi][ni] = __builtin_amdgcn_mfma_i32_16x16x64_i8(
            af[mi], bg[ni], acc[mi][ni], 0, 0, 0);
  }
#undef GLDS

  // ---- epilogue: per-row (max, sumexp) over this block's 128 cols ----
  // C frag (16x16, dtype-independent): col = l15, row = kgrp*4 + j.
  // Descale 1/16384 folded into the bias FMA.
#pragma unroll
  for (int mi = 0; mi < 4; ++mi) {
#pragma unroll
    for (int j = 0; j < 4; ++j) {
      float v0 = fmaf((float)acc[mi][0][j], INV_SCALE, bv[0]);
      float v1 = fmaf((float)acc[mi][1][j], INV_SCALE, bv[1]);
      float v2 = fmaf((float)acc[mi][2][j], INV_SCALE, bv[2]);
      float v3 = fmaf((float)acc[mi][3][j], INV_SCALE, bv[3]);
      float mx = fmaxf(fmaxf(v0, v1), fmaxf(v2, v3));
#pragma unroll
      for (int d = 1; d < 16; d <<= 1) mx = fmaxf(mx, __shfl_xor(mx, d));
      float s = __expf(v0 - mx) + __expf(v1 - mx) + __expf(v2 - mx) + __expf(v3 - mx);
#pragma unroll
      for (int d = 1; d < 16; d <<= 1) s += __shfl_xor(s, d);
      if (l15 == 0) {
        int lr = wr * 64 + mi * 16 + kgrp * 4 + j;
        redM[wc][lr] = mx;
        redS[wc][lr] = s;
      }
    }
  }
  __syncthreads();
  if (tid < BM) {
    float m0 = redM[0][tid], m1 = redM[1][tid];
    float M = fmaxf(m0, m1);
    float S = __expf(m0 - M) * redS[0][tid] + __expf(m1 - M) * redS[1][tid];
    size_t row = (size_t)mbase + tid;
    pmax[(size_t)ntile * NTOK + row] = M;   // coalesced over tid
    psum[(size_t)ntile * NTOK + row] = S;
  }
}

// merge 250 partials per row -> lse -> per-row loss
__global__ void lse_kernel(const float* __restrict__ pmax, const float* __restrict__ psum,
                           const float* __restrict__ xt, const int* __restrict__ tgt,
                           float* __restrict__ loss) {
  int row = blockIdx.x * 4 + (threadIdx.x >> 6);
  int lane = threadIdx.x & 63;
  if (row >= NTOK) return;
  float M = -3.4e38f;
  for (int i = lane; i < NT_N; i += 64) M = fmaxf(M, pmax[(size_t)i * NTOK + row]);
#pragma unroll
  for (int d = 1; d < 64; d <<= 1) M = fmaxf(M, __shfl_xor(M, d));
  float S = 0.0f;
  for (int i = lane; i < NT_N; i += 64)
    S += __expf(pmax[(size_t)i * NTOK + row] - M) * psum[(size_t)i * NTOK + row];
#pragma unroll
  for (int d = 1; d < 64; d <<= 1) S += __shfl_xor(S, d);
  if (lane == 0) {
    int tg = tgt[row];
    bool valid = (tg != IGNORE_INDEX);
    float lse = M + __logf(S);
    loss[row] = valid ? (lse - xt[row]) : 0.0f;
  }
}

__global__ void final_kernel(const float* __restrict__ loss, const int* __restrict__ tgt,
                             float* __restrict__ out) {
  __shared__ float shs[256];
  __shared__ float shc[256];
  int tid = threadIdx.x;
  float s = 0.0f, c = 0.0f;
  for (int i = tid; i < NTOK; i += 256) {
    s += loss[i];
    c += (tgt[i] != IGNORE_INDEX) ? 1.0f : 0.0f;
  }
  shs[tid] = s; shc[tid] = c;
  __syncthreads();
  for (int off = 128; off > 0; off >>= 1) {
    if (tid < off) { shs[tid] += shs[tid + off]; shc[tid] += shc[tid + off]; }
    __syncthreads();
  }
  if (tid == 0) out[0] = shs[0] / fmaxf(shc[0], 1.0f);
}

extern "C" void kernel_launch(void* const* d_in, const int* in_sizes, int n_in,
                              void* d_out, int out_size, void* d_ws, size_t ws_size,
                              hipStream_t stream) {
  const float* W    = (const float*)d_in[0];  // [32000][2048]
  const float* X    = (const float*)d_in[1];  // [4096][2048]
  const int*   tgt  = (const int*)d_in[2];    // [4096]
  const float* bias = (const float*)d_in[3];  // [32000]
  float* out = (float*)d_out;

  char* ws = (char*)d_ws;
  uint8_t* Wi8 = (uint8_t*)(ws);
  uint8_t* Xf  = (uint8_t*)(ws + 65536000);
  float* pmax  = (float*)  (ws + 73924608);
  float* psum  = (float*)  (ws + 78020608);
  float* xt    = (float*)  (ws + 82116608);
  float* loss  = (float*)  (ws + 82132992);

  cvti8_kernel<<<2048, 256, 0, stream>>>(W, (uint2*)Wi8, (size_t)VOC * HID / 8, WSCALE);
  cvtfrag_kernel<<<1024, 256, 0, stream>>>(X, (uint4*)Xf, NTOK, XSCALE);
  xt_kernel<<<NTOK / 4, 256, 0, stream>>>(X, W, bias, tgt, xt);
  gemm_lse_kernel<<<NT_M * NT_N, 256, 0, stream>>>(Xf, Wi8, bias, pmax, psum);
  lse_kernel<<<NTOK / 4, 256, 0, stream>>>(pmax, psum, xt, tgt, loss);
  final_kernel<<<1, 256, 0, stream>>>(loss, tgt, out);
}